// Round 3
// baseline (194.149 us; speedup 1.0000x reference)
//
#include <hip/hip_runtime.h>
#include <math.h>

#define NB 8
#define CH 512
#define NTOK 1024

typedef short          bf16x8 __attribute__((ext_vector_type(8)));
typedef unsigned short u16x8  __attribute__((ext_vector_type(8)));
typedef unsigned short u16x4  __attribute__((ext_vector_type(4)));
typedef unsigned short u16x2  __attribute__((ext_vector_type(2)));
typedef float          f32x4  __attribute__((ext_vector_type(4)));
typedef unsigned int   u32x2  __attribute__((ext_vector_type(2)));

__device__ __forceinline__ float bf2f(unsigned short u) {
    unsigned int x = ((unsigned int)u) << 16;
    return __builtin_bit_cast(float, x);
}
__device__ __forceinline__ unsigned short f2bf(float f) {
    unsigned int x = __builtin_bit_cast(unsigned int, f);
    x += 0x7fff + ((x >> 16) & 1);   // RNE
    return (unsigned short)(x >> 16);
}
// truncating pack of two f32 -> two bf16 (P only; common-mode cancels in O = sum(PV)/sum(P))
__device__ __forceinline__ unsigned int pack_trunc(float a, float b) {
    unsigned int ua = __builtin_bit_cast(unsigned int, a);
    unsigned int ub = __builtin_bit_cast(unsigned int, b);
    return (ua >> 16) | (ub & 0xFFFF0000u);
}

// async global->LDS, 16B per lane; LDS dest = base + lane*16 (wave-uniform base)
__device__ __forceinline__ void async16(const void* g, void* l) {
    __builtin_amdgcn_global_load_lds(
        (const __attribute__((address_space(1))) unsigned int*)g,
        (__attribute__((address_space(3))) unsigned int*)l, 16, 0, 0);
}

// ---- prep: blocks 0..255 = (b,group): GN stats + xb16 copy + GN-apply + transpose
//      blocks 256+ = weight fp32->bf16 conversion ----
__global__ __launch_bounds__(256) void prep_kernel(
    const float* __restrict__ x,
    unsigned short* __restrict__ xb16,
    const float* __restrict__ gw, const float* __restrict__ gb,
    const float* __restrict__ qkv_w, const float* __restrict__ qkv_b,
    const float* __restrict__ proj_w, const float* __restrict__ proj_b,
    unsigned short* __restrict__ wq, unsigned short* __restrict__ bq,
    unsigned short* __restrict__ wp, unsigned short* __restrict__ bp,
    unsigned short* __restrict__ xn)
{
    __shared__ float red[8];
    __shared__ float mr[2];
    int bx = blockIdx.x;
    int t = threadIdx.x;
    if (bx >= 256) {
        int i = (bx - 256) * 256 + t;
        if (i < 786432) wq[i] = f2bf(qkv_w[i]);
        else if (i < 787968) bq[i - 786432] = f2bf(qkv_b[i - 786432]);
        else if (i < 1050112) wp[i - 787968] = f2bf(proj_w[i - 787968]);
        else if (i < 1050624) bp[i - 1050112] = f2bf(proj_b[i - 1050112]);
        return;
    }
    int b = bx >> 5, g = bx & 31, c0 = g * 16;
    const f32x4* p = (const f32x4*)(x + (size_t)bx * 16384);
    u16x4* xb4 = (u16x4*)(xb16 + (size_t)bx * 16384);

    u16x2 hold[16][2];
    float s = 0.f, sq = 0.f;
    #pragma unroll
    for (int k = 0; k < 16; ++k) {
        f32x4 v = p[t + k * 256];
        u16x4 o;
        #pragma unroll
        for (int j = 0; j < 4; ++j) {
            s += v[j]; sq += v[j] * v[j];
            o[j] = f2bf(v[j]);
        }
        hold[k][0] = (u16x2){o[0], o[1]};
        hold[k][1] = (u16x2){o[2], o[3]};
        xb4[t + k * 256] = o;
    }
    for (int off = 32; off > 0; off >>= 1) {
        s  += __shfl_down(s, off);
        sq += __shfl_down(sq, off);
    }
    int lane = t & 63, wv = t >> 6;
    if (lane == 0) { red[wv] = s; red[wv + 4] = sq; }
    __syncthreads();
    if (t == 0) {
        float ts = red[0] + red[1] + red[2] + red[3];
        float tq = red[4] + red[5] + red[6] + red[7];
        float mean = ts * (1.f / 16384.f);
        float var  = tq * (1.f / 16384.f) - mean * mean;
        mr[0] = mean;
        mr[1] = rsqrtf(fmaxf(var, 0.f) + 1e-6f);
    }
    __syncthreads();
    float mean = mr[0], rstd = mr[1];

    float scale[16], shift[16];
    #pragma unroll
    for (int c = 0; c < 16; ++c) {
        scale[c] = rstd * gw[c0 + c];
        shift[c] = gb[c0 + c] - mean * scale[c];
    }
    #pragma unroll
    for (int j = 0; j < 4; ++j) {
        u16x8 r0, r1;
        #pragma unroll
        for (int c = 0; c < 8; ++c) {
            r0[c] = f2bf(bf2f(hold[c][j >> 1][j & 1]) * scale[c] + shift[c]);
            r1[c] = f2bf(bf2f(hold[c + 8][j >> 1][j & 1]) * scale[c + 8] + shift[c + 8]);
        }
        unsigned short* orow = xn + ((size_t)(b * NTOK + 4 * t + j)) * CH + c0;
        *(u16x8*)orow       = r0;
        *(u16x8*)(orow + 8) = r1;
    }
}

// ======== QKV GEMM: 128 tok x 128 out, BK=64, 2-phase double-buffered ========
__global__ __launch_bounds__(256) void qkv_gemm(
    const unsigned short* __restrict__ xn,   // [b][1024][512]
    const unsigned short* __restrict__ wq,   // [1536][512]
    const unsigned short* __restrict__ bq,   // [1536]
    unsigned short* __restrict__ qk,         // [b][1024][1024]
    unsigned short* __restrict__ vb)         // [b*8+h][64][1024]
{
    __shared__ __align__(16) unsigned short Ash[2][128 * 64];   // 2 x 16 KB
    __shared__ __align__(16) unsigned short Wsh[2][128 * 64];   // 2 x 16 KB
    int n0 = blockIdx.x * 128, o0 = blockIdx.y * 128, b = blockIdx.z;
    int t = threadIdx.x, L = t & 63, wv = t >> 6, l15 = L & 15, qd = L >> 4;
    int to0 = (wv & 1) * 64, wo0 = (wv >> 1) * 64;
    int srow = L >> 3;                 // row-within-8 for staging
    int schunk = (L & 7) ^ srow;       // pre-swizzled 16B chunk (0..7)

    f32x4 acc[4][4];
    #pragma unroll
    for (int i = 0; i < 4; ++i)
        #pragma unroll
        for (int j = 0; j < 4; ++j) acc[i][j] = (f32x4){0.f, 0.f, 0.f, 0.f};

    // stage one BK=64 tile into buffer nb: A 16 KB + W 16 KB (8 async16/thread)
    #define QSTAGE(nb, ks)                                                       \
        _Pragma("unroll")                                                        \
        for (int j = 0; j < 4; ++j) {                                            \
            int row = wv * 32 + j * 8 + srow;                                    \
            async16(xn + ((size_t)(b * NTOK + n0 + row)) * CH + (ks) * 64 + schunk * 8, \
                    &Ash[nb][(wv * 32 + j * 8) * 64]);                           \
            async16(wq + ((size_t)(o0 + row)) * CH + (ks) * 64 + schunk * 8,     \
                    &Wsh[nb][(wv * 32 + j * 8) * 64]);                           \
        }

    QSTAGE(0, 0)
    #pragma unroll
    for (int it = 0; it < 8; ++it) {
        __syncthreads();               // drains vmcnt(0): buf[it&1] ready; all waves done with buf[(it&1)^1]
        if (it < 7) { QSTAGE((it + 1) & 1, it + 1) }
        const int nb = it & 1;
        #pragma unroll
        for (int cc = 0; cc < 2; ++cc) {
            int kx = ((cc * 4 + qd) ^ (l15 & 7)) * 8;
            bf16x8 af[4], bfr[4];
            #pragma unroll
            for (int mi = 0; mi < 4; ++mi)
                af[mi] = *(const bf16x8*)&Ash[nb][(to0 + mi * 16 + l15) * 64 + kx];
            #pragma unroll
            for (int ni = 0; ni < 4; ++ni)
                bfr[ni] = *(const bf16x8*)&Wsh[nb][(wo0 + ni * 16 + l15) * 64 + kx];
            #pragma unroll
            for (int mi = 0; mi < 4; ++mi)
                #pragma unroll
                for (int ni = 0; ni < 4; ++ni)
                    acc[mi][ni] = __builtin_amdgcn_mfma_f32_16x16x32_bf16(
                        af[mi], bfr[ni], acc[mi][ni], 0, 0, 0);
        }
    }
    #undef QSTAGE

    if (o0 < 1024) {
        #pragma unroll
        for (int ni = 0; ni < 4; ++ni) {
            int o = o0 + wo0 + ni * 16 + l15;
            float bias = bf2f(bq[o]);
            #pragma unroll
            for (int mi = 0; mi < 4; ++mi) {
                int tok = n0 + to0 + mi * 16 + qd * 4;
                #pragma unroll
                for (int r = 0; r < 4; ++r)
                    qk[((size_t)b * NTOK + tok + r) * 1024 + o] = f2bf(acc[mi][ni][r] + bias);
            }
        }
    } else {
        #pragma unroll
        for (int ni = 0; ni < 4; ++ni) {
            int oo = o0 - 1024 + wo0 + ni * 16 + l15;
            int h = oo >> 6, c = oo & 63;
            float bias = bf2f(bq[1024 + oo]);
            #pragma unroll
            for (int mi = 0; mi < 4; ++mi) {
                int tok = n0 + to0 + mi * 16 + qd * 4;
                u16x4 pk;
                #pragma unroll
                for (int r = 0; r < 4; ++r) pk[r] = f2bf(acc[mi][ni][r] + bias);
                *(u16x4*)&vb[((size_t)(b * 8 + h) * 64 + c) * NTOK + tok] = pk;
            }
        }
    }
}

// ====== proj GEMM: 64 tok x 128 out, BK=64, 2-phase double-buffered ======
__global__ __launch_bounds__(256) void proj_gemm(
    const unsigned short* __restrict__ ao,   // qk: cols [0,512) attn out, pitch 1024
    const unsigned short* __restrict__ wp,   // [512][512]
    const unsigned short* __restrict__ bp,   // [512]
    const unsigned short* __restrict__ xb16, // residual bf16 [b][512][1024]
    float* __restrict__ out)                 // [b][512][1024]
{
    __shared__ __align__(16) unsigned short Ash[2][64 * 64];    // 2 x 8 KB
    __shared__ __align__(16) unsigned short Wsh[2][128 * 64];   // 2 x 16 KB
    int n0 = blockIdx.x * 64, o0 = blockIdx.y * 128, b = blockIdx.z;
    int t = threadIdx.x, L = t & 63, wv = t >> 6, l15 = L & 15, qd = L >> 4;
    int to0 = (wv & 1) * 32, wo0 = (wv >> 1) * 64;
    int srow = L >> 3;
    int schunk = (L & 7) ^ srow;

    f32x4 acc[2][4];
    #pragma unroll
    for (int i = 0; i < 2; ++i)
        #pragma unroll
        for (int j = 0; j < 4; ++j) acc[i][j] = (f32x4){0.f, 0.f, 0.f, 0.f};

    #define PSTAGE(nb, ks)                                                       \
        _Pragma("unroll")                                                        \
        for (int j = 0; j < 2; ++j) {                                            \
            int row = wv * 16 + j * 8 + srow;                                    \
            async16(ao + ((size_t)(b * NTOK + n0 + row)) * 1024 + (ks) * 64 + schunk * 8, \
                    &Ash[nb][(wv * 16 + j * 8) * 64]);                           \
        }                                                                        \
        _Pragma("unroll")                                                        \
        for (int j = 0; j < 4; ++j) {                                            \
            int row = wv * 32 + j * 8 + srow;                                    \
            async16(wp + ((size_t)(o0 + row)) * CH + (ks) * 64 + schunk * 8,     \
                    &Wsh[nb][(wv * 32 + j * 8) * 64]);                           \
        }

    PSTAGE(0, 0)
    #pragma unroll
    for (int it = 0; it < 8; ++it) {
        __syncthreads();
        if (it < 7) { PSTAGE((it + 1) & 1, it + 1) }
        const int nb = it & 1;
        #pragma unroll
        for (int cc = 0; cc < 2; ++cc) {
            int kx = ((cc * 4 + qd) ^ (l15 & 7)) * 8;
            bf16x8 af[2], bfr[4];
            #pragma unroll
            for (int mi = 0; mi < 2; ++mi)
                af[mi] = *(const bf16x8*)&Ash[nb][(to0 + mi * 16 + l15) * 64 + kx];
            #pragma unroll
            for (int ni = 0; ni < 4; ++ni)
                bfr[ni] = *(const bf16x8*)&Wsh[nb][(wo0 + ni * 16 + l15) * 64 + kx];
            #pragma unroll
            for (int mi = 0; mi < 2; ++mi)
                #pragma unroll
                for (int ni = 0; ni < 4; ++ni)
                    acc[mi][ni] = __builtin_amdgcn_mfma_f32_16x16x32_bf16(
                        af[mi], bfr[ni], acc[mi][ni], 0, 0, 0);
        }
    }
    #undef PSTAGE

    #pragma unroll
    for (int ni = 0; ni < 4; ++ni) {
        int o = o0 + wo0 + ni * 16 + l15;
        float bias = bf2f(bp[o]);
        #pragma unroll
        for (int mi = 0; mi < 2; ++mi) {
            int tok = n0 + to0 + mi * 16 + qd * 4;
            size_t base = ((size_t)(b * CH + o)) * NTOK + tok;
            u16x4 res = *(const u16x4*)(xb16 + base);
            f32x4 vv;
            #pragma unroll
            for (int r = 0; r < 4; ++r) vv[r] = acc[mi][ni][r] + bias + bf2f(res[r]);
            *(f32x4*)(out + base) = vv;
        }
    }
}

// ===== MFMA flash attention: KV tile 64, 2-phase double-buffered + setprio =====
__global__ __launch_bounds__(256) void attn_kernel(
    unsigned short* __restrict__ qk, const unsigned short* __restrict__ vb)
{
    __shared__ __align__(16) unsigned short Kt[2][64 * 64];   // 2 x 8 KB (double buffer)
    __shared__ __align__(16) unsigned short Vt[2][64 * 64];   // 2 x 8 KB
    __shared__ __align__(16) unsigned short Psc[4][32 * 64];  // 16 KB

    int bh = blockIdx.x, b = bh >> 3, h = bh & 7;
    int q0 = blockIdx.y * 128;
    int t = threadIdx.x, L = t & 63, wv = t >> 6, l15 = L & 15, qd = L >> 4;
    int srow = L >> 3;
    int scol = ((L & 7) ^ srow) * 8;
    int key8 = (l15 & 7) * 8;

    const unsigned short* qkb = qk + (size_t)b * NTOK * 1024;
    const unsigned short* vbase = vb + (size_t)bh * 64 * NTOK;

    const float QSC = 0.125f * 1.44269504f;
    bf16x8 qf[2][2];
    #pragma unroll
    for (int nt = 0; nt < 2; ++nt)
        #pragma unroll
        for (int cc = 0; cc < 2; ++cc) {
            const unsigned short* qrow =
                qkb + (size_t)(q0 + wv * 32 + nt * 16 + l15) * 1024 + h * 64 + cc * 32 + qd * 8;
            u16x8 u = *(const u16x8*)qrow;
            bf16x8 s;
            #pragma unroll
            for (int j = 0; j < 8; ++j) s[j] = (short)f2bf(bf2f(u[j]) * QSC);
            qf[nt][cc] = s;
        }

    f32x4 Oacc[2][4];
    #pragma unroll
    for (int i = 0; i < 2; ++i)
        #pragma unroll
        for (int j = 0; j < 4; ++j) Oacc[i][j] = (f32x4){0.f, 0.f, 0.f, 0.f};
    float lsum[2] = {0.f, 0.f};

    // stage a 64-key tile (K 8 KB + V 8 KB, 4 async16/thread) into buffer nb
    #define ASTAGE(nb, m0)                                                           \
        _Pragma("unroll")                                                            \
        for (int j = 0; j < 2; ++j) {                                                \
            int is = wv * 2 + j;                                                     \
            async16(qkb + (size_t)((m0) + is * 8 + srow) * 1024 + 512 + h * 64 + scol, \
                    &Kt[nb][is * 512]);                                              \
            async16(vbase + (size_t)(is * 8 + srow) * 1024 + (m0) + scol,            \
                    &Vt[nb][is * 512]);                                              \
        }

    ASTAGE(0, 0)
    #pragma unroll
    for (int it = 0; it < 16; ++it) {
        __syncthreads();              // vmcnt(0) drain: buf[it&1] loaded; all waves done with other buf
        if (it < 15) { ASTAGE((it + 1) & 1, (it + 1) * 64) }
        const int nb = it & 1;

        // ---- QK^T (16 MFMA) ----
        f32x4 st[4][2];
        #pragma unroll
        for (int mt = 0; mt < 4; ++mt)
            #pragma unroll
            for (int nt = 0; nt < 2; ++nt) st[mt][nt] = (f32x4){0.f, 0.f, 0.f, 0.f};
        __builtin_amdgcn_s_setprio(1);
        #pragma unroll
        for (int cc = 0; cc < 2; ++cc) {
            #pragma unroll
            for (int mt = 0; mt < 4; ++mt) {
                bf16x8 a = *(const bf16x8*)&Kt[nb][(mt * 16 + l15) * 64 + ((cc * 32 + qd * 8) ^ key8)];
                #pragma unroll
                for (int nt = 0; nt < 2; ++nt)
                    st[mt][nt] = __builtin_amdgcn_mfma_f32_16x16x32_bf16(a, qf[nt][cc], st[mt][nt], 0, 0, 0);
            }
        }
        __builtin_amdgcn_s_setprio(0);

        // ---- softmax numerator + pack to LDS ----
        #pragma unroll
        for (int mt = 0; mt < 4; ++mt)
            #pragma unroll
            for (int nt = 0; nt < 2; ++nt) {
                float p0 = __builtin_amdgcn_exp2f(st[mt][nt][0]);
                float p1 = __builtin_amdgcn_exp2f(st[mt][nt][1]);
                float p2 = __builtin_amdgcn_exp2f(st[mt][nt][2]);
                float p3 = __builtin_amdgcn_exp2f(st[mt][nt][3]);
                lsum[nt] += (p0 + p1) + (p2 + p3);
                u32x2 pw = { pack_trunc(p0, p1), pack_trunc(p2, p3) };
                *(u32x2*)&Psc[wv][(nt * 16 + l15) * 64 + ((mt * 16 + 4 * qd) ^ key8)] = pw;
            }

        // ---- PV (16 MFMA) ----
        __builtin_amdgcn_s_setprio(1);
        #pragma unroll
        for (int mk = 0; mk < 2; ++mk) {
            bf16x8 ap[2];
            #pragma unroll
            for (int nt = 0; nt < 2; ++nt)
                ap[nt] = *(const bf16x8*)&Psc[wv][(nt * 16 + l15) * 64 + ((mk * 32 + qd * 8) ^ key8)];
            #pragma unroll
            for (int ct = 0; ct < 4; ++ct) {
                bf16x8 bv = *(const bf16x8*)&Vt[nb][(ct * 16 + l15) * 64 + ((mk * 32 + qd * 8) ^ key8)];
                #pragma unroll
                for (int nt = 0; nt < 2; ++nt)
                    Oacc[nt][ct] = __builtin_amdgcn_mfma_f32_16x16x32_bf16(ap[nt], bv, Oacc[nt][ct], 0, 0, 0);
            }
        }
        __builtin_amdgcn_s_setprio(0);
    }
    #undef ASTAGE

    #pragma unroll
    for (int nt = 0; nt < 2; ++nt) {
        lsum[nt] += __shfl_xor(lsum[nt], 16);
        lsum[nt] += __shfl_xor(lsum[nt], 32);
        float inv = 1.f / lsum[nt];
        #pragma unroll
        for (int r = 0; r < 4; ++r) {
            float ir = __shfl(inv, 4 * qd + r);
            int n = q0 + wv * 32 + nt * 16 + qd * 4 + r;
            unsigned short* orow = qk + ((size_t)b * NTOK + n) * 1024 + h * 64;
            #pragma unroll
            for (int ct = 0; ct < 4; ++ct)
                orow[ct * 16 + l15] = f2bf(Oacc[nt][ct][r] * ir);
        }
    }
}

extern "C" void kernel_launch(void* const* d_in, const int* in_sizes, int n_in,
                              void* d_out, int out_size, void* d_ws, size_t ws_size,
                              hipStream_t stream) {
    const float* x      = (const float*)d_in[0];
    const float* norm_w = (const float*)d_in[1];
    const float* norm_b = (const float*)d_in[2];
    const float* qkv_w  = (const float*)d_in[3];
    const float* qkv_b  = (const float*)d_in[4];
    const float* proj_w = (const float*)d_in[5];
    const float* proj_b = (const float*)d_in[6];
    float* out = (float*)d_out;

    // ws: qk 16MB | vb 8MB | wp 512KB | bp 1KB | pad | xb16 16MB
    const size_t QK_B = (size_t)NB * NTOK * 1024 * 2;        // 16,777,216
    const size_t VB_B = (size_t)NB * 8 * 64 * NTOK * 2;      //  8,388,608
    const size_t XB_OFF = QK_B + VB_B + 1048576;
    if (ws_size < XB_OFF + (size_t)NB * CH * NTOK * 2) return;
    unsigned short* qk = (unsigned short*)d_ws;
    unsigned short* vb = (unsigned short*)((char*)d_ws + QK_B);
    unsigned short* wp = (unsigned short*)((char*)d_ws + QK_B + VB_B);
    unsigned short* bp = (unsigned short*)((char*)d_ws + QK_B + VB_B + 524288);
    unsigned short* xb16 = (unsigned short*)((char*)d_ws + XB_OFF);

    // d_out scratch (dead until proj writes): xn 8 MB | wq 1.5 MB | bq 3 KB
    unsigned short* xn = (unsigned short*)d_out;
    unsigned short* wq = (unsigned short*)((char*)d_out + 8388608);
    unsigned short* bq = (unsigned short*)((char*)d_out + 9961472);

    prep_kernel<<<dim3(4361), dim3(256), 0, stream>>>(
        x, xb16, norm_w, norm_b, qkv_w, qkv_b, proj_w, proj_b, wq, bq, wp, bp, xn);
    qkv_gemm<<<dim3(8, 12, NB), dim3(256), 0, stream>>>(xn, wq, bq, qk, vb);
    attn_kernel<<<dim3(64, 8, 1), dim3(256), 0, stream>>>(qk, vb);
    proj_gemm<<<dim3(16, 4, NB), dim3(256), 0, stream>>>(qk, wp, bp, xb16, out);
}

// Round 4
// 149.877 us; speedup vs baseline: 1.2954x; 1.2954x over previous
//
#include <hip/hip_runtime.h>
#include <math.h>

#define NB 8
#define CH 512
#define NTOK 1024

typedef short          bf16x8 __attribute__((ext_vector_type(8)));
typedef unsigned short u16x8  __attribute__((ext_vector_type(8)));
typedef unsigned short u16x4  __attribute__((ext_vector_type(4)));
typedef unsigned short u16x2  __attribute__((ext_vector_type(2)));
typedef float          f32x4  __attribute__((ext_vector_type(4)));
typedef unsigned int   u32x2  __attribute__((ext_vector_type(2)));

__device__ __forceinline__ float bf2f(unsigned short u) {
    unsigned int x = ((unsigned int)u) << 16;
    return __builtin_bit_cast(float, x);
}
__device__ __forceinline__ unsigned short f2bf(float f) {
    unsigned int x = __builtin_bit_cast(unsigned int, f);
    x += 0x7fff + ((x >> 16) & 1);   // RNE
    return (unsigned short)(x >> 16);
}
// truncating pack of two f32 -> two bf16 (P only; common-mode cancels in O = sum(PV)/sum(P))
__device__ __forceinline__ unsigned int pack_trunc(float a, float b) {
    unsigned int ua = __builtin_bit_cast(unsigned int, a);
    unsigned int ub = __builtin_bit_cast(unsigned int, b);
    return (ua >> 16) | (ub & 0xFFFF0000u);
}

// async global->LDS, 16B per lane; LDS dest = base + lane*16 (wave-uniform base)
__device__ __forceinline__ void async16(const void* g, void* l) {
    __builtin_amdgcn_global_load_lds(
        (const __attribute__((address_space(1))) unsigned int*)g,
        (__attribute__((address_space(3))) unsigned int*)l, 16, 0, 0);
}

// ---- prep: blocks 0..255 = (b,group): GN stats + xb16 copy + GN-apply + transpose
//      blocks 256+ = weight fp32->bf16 conversion ----
__global__ __launch_bounds__(256) void prep_kernel(
    const float* __restrict__ x,
    unsigned short* __restrict__ xb16,
    const float* __restrict__ gw, const float* __restrict__ gb,
    const float* __restrict__ qkv_w, const float* __restrict__ qkv_b,
    const float* __restrict__ proj_w, const float* __restrict__ proj_b,
    unsigned short* __restrict__ wq, unsigned short* __restrict__ bq,
    unsigned short* __restrict__ wp, unsigned short* __restrict__ bp,
    unsigned short* __restrict__ xn)
{
    __shared__ float red[8];
    __shared__ float mr[2];
    int bx = blockIdx.x;
    int t = threadIdx.x;
    if (bx >= 256) {
        int i = (bx - 256) * 256 + t;
        if (i < 786432) wq[i] = f2bf(qkv_w[i]);
        else if (i < 787968) bq[i - 786432] = f2bf(qkv_b[i - 786432]);
        else if (i < 1050112) wp[i - 787968] = f2bf(proj_w[i - 787968]);
        else if (i < 1050624) bp[i - 1050112] = f2bf(proj_b[i - 1050112]);
        return;
    }
    int b = bx >> 5, g = bx & 31, c0 = g * 16;
    const f32x4* p = (const f32x4*)(x + (size_t)bx * 16384);
    u16x4* xb4 = (u16x4*)(xb16 + (size_t)bx * 16384);

    u16x2 hold[16][2];
    float s = 0.f, sq = 0.f;
    #pragma unroll
    for (int k = 0; k < 16; ++k) {
        f32x4 v = p[t + k * 256];
        u16x4 o;
        #pragma unroll
        for (int j = 0; j < 4; ++j) {
            s += v[j]; sq += v[j] * v[j];
            o[j] = f2bf(v[j]);
        }
        hold[k][0] = (u16x2){o[0], o[1]};
        hold[k][1] = (u16x2){o[2], o[3]};
        xb4[t + k * 256] = o;
    }
    for (int off = 32; off > 0; off >>= 1) {
        s  += __shfl_down(s, off);
        sq += __shfl_down(sq, off);
    }
    int lane = t & 63, wv = t >> 6;
    if (lane == 0) { red[wv] = s; red[wv + 4] = sq; }
    __syncthreads();
    if (t == 0) {
        float ts = red[0] + red[1] + red[2] + red[3];
        float tq = red[4] + red[5] + red[6] + red[7];
        float mean = ts * (1.f / 16384.f);
        float var  = tq * (1.f / 16384.f) - mean * mean;
        mr[0] = mean;
        mr[1] = rsqrtf(fmaxf(var, 0.f) + 1e-6f);
    }
    __syncthreads();
    float mean = mr[0], rstd = mr[1];

    float scale[16], shift[16];
    #pragma unroll
    for (int c = 0; c < 16; ++c) {
        scale[c] = rstd * gw[c0 + c];
        shift[c] = gb[c0 + c] - mean * scale[c];
    }
    #pragma unroll
    for (int j = 0; j < 4; ++j) {
        u16x8 r0, r1;
        #pragma unroll
        for (int c = 0; c < 8; ++c) {
            r0[c] = f2bf(bf2f(hold[c][j >> 1][j & 1]) * scale[c] + shift[c]);
            r1[c] = f2bf(bf2f(hold[c + 8][j >> 1][j & 1]) * scale[c + 8] + shift[c + 8]);
        }
        unsigned short* orow = xn + ((size_t)(b * NTOK + 4 * t + j)) * CH + c0;
        *(u16x8*)orow       = r0;
        *(u16x8*)(orow + 8) = r1;
    }
}

// ======== QKV GEMM: 128 tok x 128 out, BK=64, 2-phase double-buffered ========
__global__ __launch_bounds__(256) void qkv_gemm(
    const unsigned short* __restrict__ xn,   // [b][1024][512]
    const unsigned short* __restrict__ wq,   // [1536][512]
    const unsigned short* __restrict__ bq,   // [1536]
    unsigned short* __restrict__ qk,         // [b][1024][1024]
    unsigned short* __restrict__ vb)         // [b*8+h][64][1024]
{
    __shared__ __align__(16) unsigned short Ash[2][128 * 64];   // 2 x 16 KB
    __shared__ __align__(16) unsigned short Wsh[2][128 * 64];   // 2 x 16 KB
    int n0 = blockIdx.x * 128, o0 = blockIdx.y * 128, b = blockIdx.z;
    int t = threadIdx.x, L = t & 63, wv = t >> 6, l15 = L & 15, qd = L >> 4;
    int to0 = (wv & 1) * 64, wo0 = (wv >> 1) * 64;
    int srow = L >> 3;                 // row-within-8 for staging
    int schunk = (L & 7) ^ srow;       // pre-swizzled 16B chunk (0..7)

    f32x4 acc[4][4];
    #pragma unroll
    for (int i = 0; i < 4; ++i)
        #pragma unroll
        for (int j = 0; j < 4; ++j) acc[i][j] = (f32x4){0.f, 0.f, 0.f, 0.f};

    // stage one BK=64 tile into buffer nb: A 16 KB + W 16 KB (8 async16/thread)
    #define QSTAGE(nb, ks)                                                       \
        _Pragma("unroll")                                                        \
        for (int j = 0; j < 4; ++j) {                                            \
            int row = wv * 32 + j * 8 + srow;                                    \
            async16(xn + ((size_t)(b * NTOK + n0 + row)) * CH + (ks) * 64 + schunk * 8, \
                    &Ash[nb][(wv * 32 + j * 8) * 64]);                           \
            async16(wq + ((size_t)(o0 + row)) * CH + (ks) * 64 + schunk * 8,     \
                    &Wsh[nb][(wv * 32 + j * 8) * 64]);                           \
        }

    // consume buffer nb (64 k-depth = 2 cc chunks, 32 MFMA)
    #define QCOMP(nb)                                                            \
        _Pragma("unroll")                                                        \
        for (int cc = 0; cc < 2; ++cc) {                                         \
            int kx = ((cc * 4 + qd) ^ (l15 & 7)) * 8;                            \
            bf16x8 af[4], bfr[4];                                                \
            _Pragma("unroll")                                                    \
            for (int mi = 0; mi < 4; ++mi)                                       \
                af[mi] = *(const bf16x8*)&Ash[nb][(to0 + mi * 16 + l15) * 64 + kx]; \
            _Pragma("unroll")                                                    \
            for (int ni = 0; ni < 4; ++ni)                                       \
                bfr[ni] = *(const bf16x8*)&Wsh[nb][(wo0 + ni * 16 + l15) * 64 + kx]; \
            _Pragma("unroll")                                                    \
            for (int mi = 0; mi < 4; ++mi)                                       \
                _Pragma("unroll")                                                \
                for (int ni = 0; ni < 4; ++ni)                                   \
                    acc[mi][ni] = __builtin_amdgcn_mfma_f32_16x16x32_bf16(       \
                        af[mi], bfr[ni], acc[mi][ni], 0, 0, 0);                  \
        }

    QSTAGE(0, 0)
    #pragma unroll 1
    for (int ks = 0; ks < 8; ks += 2) {
        __syncthreads();                 // buf0 (chunk ks) ready; buf1 free
        QSTAGE(1, ks + 1)
        QCOMP(0)
        __syncthreads();                 // buf1 ready; buf0 free
        if (ks < 6) { QSTAGE(0, ks + 2) }
        QCOMP(1)
    }
    #undef QSTAGE
    #undef QCOMP

    if (o0 < 1024) {
        #pragma unroll
        for (int ni = 0; ni < 4; ++ni) {
            int o = o0 + wo0 + ni * 16 + l15;
            float bias = bf2f(bq[o]);
            #pragma unroll
            for (int mi = 0; mi < 4; ++mi) {
                int tok = n0 + to0 + mi * 16 + qd * 4;
                #pragma unroll
                for (int r = 0; r < 4; ++r)
                    qk[((size_t)b * NTOK + tok + r) * 1024 + o] = f2bf(acc[mi][ni][r] + bias);
            }
        }
    } else {
        #pragma unroll
        for (int ni = 0; ni < 4; ++ni) {
            int oo = o0 - 1024 + wo0 + ni * 16 + l15;
            int h = oo >> 6, c = oo & 63;
            float bias = bf2f(bq[1024 + oo]);
            #pragma unroll
            for (int mi = 0; mi < 4; ++mi) {
                int tok = n0 + to0 + mi * 16 + qd * 4;
                u16x4 pk;
                #pragma unroll
                for (int r = 0; r < 4; ++r) pk[r] = f2bf(acc[mi][ni][r] + bias);
                *(u16x4*)&vb[((size_t)(b * 8 + h) * 64 + c) * NTOK + tok] = pk;
            }
        }
    }
}

// ====== proj GEMM: 64 tok x 128 out, BK=64, 2-phase double-buffered ======
__global__ __launch_bounds__(256) void proj_gemm(
    const unsigned short* __restrict__ ao,   // qk: cols [0,512) attn out, pitch 1024
    const unsigned short* __restrict__ wp,   // [512][512]
    const unsigned short* __restrict__ bp,   // [512]
    const unsigned short* __restrict__ xb16, // residual bf16 [b][512][1024]
    float* __restrict__ out)                 // [b][512][1024]
{
    __shared__ __align__(16) unsigned short Ash[2][64 * 64];    // 2 x 8 KB
    __shared__ __align__(16) unsigned short Wsh[2][128 * 64];   // 2 x 16 KB
    int n0 = blockIdx.x * 64, o0 = blockIdx.y * 128, b = blockIdx.z;
    int t = threadIdx.x, L = t & 63, wv = t >> 6, l15 = L & 15, qd = L >> 4;
    int to0 = (wv & 1) * 32, wo0 = (wv >> 1) * 64;
    int srow = L >> 3;
    int schunk = (L & 7) ^ srow;

    f32x4 acc[2][4];
    #pragma unroll
    for (int i = 0; i < 2; ++i)
        #pragma unroll
        for (int j = 0; j < 4; ++j) acc[i][j] = (f32x4){0.f, 0.f, 0.f, 0.f};

    #define PSTAGE(nb, ks)                                                       \
        _Pragma("unroll")                                                        \
        for (int j = 0; j < 2; ++j) {                                            \
            int row = wv * 16 + j * 8 + srow;                                    \
            async16(ao + ((size_t)(b * NTOK + n0 + row)) * 1024 + (ks) * 64 + schunk * 8, \
                    &Ash[nb][(wv * 16 + j * 8) * 64]);                           \
        }                                                                        \
        _Pragma("unroll")                                                        \
        for (int j = 0; j < 4; ++j) {                                            \
            int row = wv * 32 + j * 8 + srow;                                    \
            async16(wp + ((size_t)(o0 + row)) * CH + (ks) * 64 + schunk * 8,     \
                    &Wsh[nb][(wv * 32 + j * 8) * 64]);                           \
        }

    #define PCOMP(nb)                                                            \
        _Pragma("unroll")                                                        \
        for (int cc = 0; cc < 2; ++cc) {                                         \
            int kx = ((cc * 4 + qd) ^ (l15 & 7)) * 8;                            \
            bf16x8 af[2], bfr[4];                                                \
            _Pragma("unroll")                                                    \
            for (int mi = 0; mi < 2; ++mi)                                       \
                af[mi] = *(const bf16x8*)&Ash[nb][(to0 + mi * 16 + l15) * 64 + kx]; \
            _Pragma("unroll")                                                    \
            for (int ni = 0; ni < 4; ++ni)                                       \
                bfr[ni] = *(const bf16x8*)&Wsh[nb][(wo0 + ni * 16 + l15) * 64 + kx]; \
            _Pragma("unroll")                                                    \
            for (int mi = 0; mi < 2; ++mi)                                       \
                _Pragma("unroll")                                                \
                for (int ni = 0; ni < 4; ++ni)                                   \
                    acc[mi][ni] = __builtin_amdgcn_mfma_f32_16x16x32_bf16(       \
                        af[mi], bfr[ni], acc[mi][ni], 0, 0, 0);                  \
        }

    PSTAGE(0, 0)
    #pragma unroll 1
    for (int ks = 0; ks < 8; ks += 2) {
        __syncthreads();
        PSTAGE(1, ks + 1)
        PCOMP(0)
        __syncthreads();
        if (ks < 6) { PSTAGE(0, ks + 2) }
        PCOMP(1)
    }
    #undef PSTAGE
    #undef PCOMP

    #pragma unroll
    for (int ni = 0; ni < 4; ++ni) {
        int o = o0 + wo0 + ni * 16 + l15;
        float bias = bf2f(bp[o]);
        #pragma unroll
        for (int mi = 0; mi < 2; ++mi) {
            int tok = n0 + to0 + mi * 16 + qd * 4;
            size_t base = ((size_t)(b * CH + o)) * NTOK + tok;
            u16x4 res = *(const u16x4*)(xb16 + base);
            f32x4 vv;
            #pragma unroll
            for (int r = 0; r < 4; ++r) vv[r] = acc[mi][ni][r] + bias + bf2f(res[r]);
            *(f32x4*)(out + base) = vv;
        }
    }
}

// ===== MFMA flash attention: KV tile 64, 2-phase double-buffered (no setprio) =====
__global__ __launch_bounds__(256) void attn_kernel(
    unsigned short* __restrict__ qk, const unsigned short* __restrict__ vb)
{
    __shared__ __align__(16) unsigned short Kt[2][64 * 64];   // 2 x 8 KB (double buffer)
    __shared__ __align__(16) unsigned short Vt[2][64 * 64];   // 2 x 8 KB
    __shared__ __align__(16) unsigned short Psc[4][32 * 64];  // 16 KB

    int bh = blockIdx.x, b = bh >> 3, h = bh & 7;
    int q0 = blockIdx.y * 128;
    int t = threadIdx.x, L = t & 63, wv = t >> 6, l15 = L & 15, qd = L >> 4;
    int srow = L >> 3;
    int scol = ((L & 7) ^ srow) * 8;
    int key8 = (l15 & 7) * 8;

    const unsigned short* qkb = qk + (size_t)b * NTOK * 1024;
    const unsigned short* vbase = vb + (size_t)bh * 64 * NTOK;

    const float QSC = 0.125f * 1.44269504f;
    bf16x8 qf[2][2];
    #pragma unroll
    for (int nt = 0; nt < 2; ++nt)
        #pragma unroll
        for (int cc = 0; cc < 2; ++cc) {
            const unsigned short* qrow =
                qkb + (size_t)(q0 + wv * 32 + nt * 16 + l15) * 1024 + h * 64 + cc * 32 + qd * 8;
            u16x8 u = *(const u16x8*)qrow;
            bf16x8 s;
            #pragma unroll
            for (int j = 0; j < 8; ++j) s[j] = (short)f2bf(bf2f(u[j]) * QSC);
            qf[nt][cc] = s;
        }

    f32x4 Oacc[2][4];
    #pragma unroll
    for (int i = 0; i < 2; ++i)
        #pragma unroll
        for (int j = 0; j < 4; ++j) Oacc[i][j] = (f32x4){0.f, 0.f, 0.f, 0.f};
    float lsum[2] = {0.f, 0.f};

    // stage a 64-key tile (K 8 KB + V 8 KB, 4 async16/thread) into buffer nb
    #define ASTAGE(nb, m0)                                                           \
        _Pragma("unroll")                                                            \
        for (int j = 0; j < 2; ++j) {                                                \
            int is = wv * 2 + j;                                                     \
            async16(qkb + (size_t)((m0) + is * 8 + srow) * 1024 + 512 + h * 64 + scol, \
                    &Kt[nb][is * 512]);                                              \
            async16(vbase + (size_t)(is * 8 + srow) * 1024 + (m0) + scol,            \
                    &Vt[nb][is * 512]);                                              \
        }

    // consume buffer nb: QK^T (16 MFMA) + exp/pack + PV (16 MFMA)
    #define ACOMP(nb)                                                                \
    {                                                                                \
        f32x4 st[4][2];                                                              \
        _Pragma("unroll")                                                            \
        for (int mt = 0; mt < 4; ++mt)                                               \
            _Pragma("unroll")                                                        \
            for (int nt = 0; nt < 2; ++nt) st[mt][nt] = (f32x4){0.f, 0.f, 0.f, 0.f}; \
        _Pragma("unroll")                                                            \
        for (int cc = 0; cc < 2; ++cc) {                                             \
            _Pragma("unroll")                                                        \
            for (int mt = 0; mt < 4; ++mt) {                                         \
                bf16x8 a = *(const bf16x8*)&Kt[nb][(mt * 16 + l15) * 64 + ((cc * 32 + qd * 8) ^ key8)]; \
                _Pragma("unroll")                                                    \
                for (int nt = 0; nt < 2; ++nt)                                       \
                    st[mt][nt] = __builtin_amdgcn_mfma_f32_16x16x32_bf16(a, qf[nt][cc], st[mt][nt], 0, 0, 0); \
            }                                                                        \
        }                                                                            \
        _Pragma("unroll")                                                            \
        for (int mt = 0; mt < 4; ++mt)                                               \
            _Pragma("unroll")                                                        \
            for (int nt = 0; nt < 2; ++nt) {                                         \
                float p0 = __builtin_amdgcn_exp2f(st[mt][nt][0]);                    \
                float p1 = __builtin_amdgcn_exp2f(st[mt][nt][1]);                    \
                float p2 = __builtin_amdgcn_exp2f(st[mt][nt][2]);                    \
                float p3 = __builtin_amdgcn_exp2f(st[mt][nt][3]);                    \
                lsum[nt] += (p0 + p1) + (p2 + p3);                                   \
                u32x2 pw = { pack_trunc(p0, p1), pack_trunc(p2, p3) };               \
                *(u32x2*)&Psc[wv][(nt * 16 + l15) * 64 + ((mt * 16 + 4 * qd) ^ key8)] = pw; \
            }                                                                        \
        _Pragma("unroll")                                                            \
        for (int mk = 0; mk < 2; ++mk) {                                             \
            bf16x8 ap[2];                                                            \
            _Pragma("unroll")                                                        \
            for (int nt = 0; nt < 2; ++nt)                                           \
                ap[nt] = *(const bf16x8*)&Psc[wv][(nt * 16 + l15) * 64 + ((mk * 32 + qd * 8) ^ key8)]; \
            _Pragma("unroll")                                                        \
            for (int ct = 0; ct < 4; ++ct) {                                         \
                bf16x8 bv = *(const bf16x8*)&Vt[nb][(ct * 16 + l15) * 64 + ((mk * 32 + qd * 8) ^ key8)]; \
                _Pragma("unroll")                                                    \
                for (int nt = 0; nt < 2; ++nt)                                       \
                    Oacc[nt][ct] = __builtin_amdgcn_mfma_f32_16x16x32_bf16(ap[nt], bv, Oacc[nt][ct], 0, 0, 0); \
            }                                                                        \
        }                                                                            \
    }

    ASTAGE(0, 0)
    #pragma unroll 1
    for (int m0 = 0; m0 < NTOK; m0 += 128) {
        __syncthreads();                   // buf0 (keys m0) ready; buf1 free
        ASTAGE(1, m0 + 64)                 // prefetch keys m0+64 (always < NTOK)
        ACOMP(0)
        __syncthreads();                   // buf1 ready; buf0 free
        if (m0 + 128 < NTOK) { ASTAGE(0, m0 + 128) }
        ACOMP(1)
    }
    #undef ASTAGE
    #undef ACOMP

    #pragma unroll
    for (int nt = 0; nt < 2; ++nt) {
        lsum[nt] += __shfl_xor(lsum[nt], 16);
        lsum[nt] += __shfl_xor(lsum[nt], 32);
        float inv = 1.f / lsum[nt];
        #pragma unroll
        for (int r = 0; r < 4; ++r) {
            float ir = __shfl(inv, 4 * qd + r);
            int n = q0 + wv * 32 + nt * 16 + qd * 4 + r;
            unsigned short* orow = qk + ((size_t)b * NTOK + n) * 1024 + h * 64;
            #pragma unroll
            for (int ct = 0; ct < 4; ++ct)
                orow[ct * 16 + l15] = f2bf(Oacc[nt][ct][r] * ir);
        }
    }
}

extern "C" void kernel_launch(void* const* d_in, const int* in_sizes, int n_in,
                              void* d_out, int out_size, void* d_ws, size_t ws_size,
                              hipStream_t stream) {
    const float* x      = (const float*)d_in[0];
    const float* norm_w = (const float*)d_in[1];
    const float* norm_b = (const float*)d_in[2];
    const float* qkv_w  = (const float*)d_in[3];
    const float* qkv_b  = (const float*)d_in[4];
    const float* proj_w = (const float*)d_in[5];
    const float* proj_b = (const float*)d_in[6];
    float* out = (float*)d_out;

    // ws: qk 16MB | vb 8MB | wp 512KB | bp 1KB | pad | xb16 16MB
    const size_t QK_B = (size_t)NB * NTOK * 1024 * 2;        // 16,777,216
    const size_t VB_B = (size_t)NB * 8 * 64 * NTOK * 2;      //  8,388,608
    const size_t XB_OFF = QK_B + VB_B + 1048576;
    if (ws_size < XB_OFF + (size_t)NB * CH * NTOK * 2) return;
    unsigned short* qk = (unsigned short*)d_ws;
    unsigned short* vb = (unsigned short*)((char*)d_ws + QK_B);
    unsigned short* wp = (unsigned short*)((char*)d_ws + QK_B + VB_B);
    unsigned short* bp = (unsigned short*)((char*)d_ws + QK_B + VB_B + 524288);
    unsigned short* xb16 = (unsigned short*)((char*)d_ws + XB_OFF);

    // d_out scratch (dead until proj writes): xn 8 MB | wq 1.5 MB | bq 3 KB
    unsigned short* xn = (unsigned short*)d_out;
    unsigned short* wq = (unsigned short*)((char*)d_out + 8388608);
    unsigned short* bq = (unsigned short*)((char*)d_out + 9961472);

    prep_kernel<<<dim3(4361), dim3(256), 0, stream>>>(
        x, xb16, norm_w, norm_b, qkv_w, qkv_b, proj_w, proj_b, wq, bq, wp, bp, xn);
    qkv_gemm<<<dim3(8, 12, NB), dim3(256), 0, stream>>>(xn, wq, bq, qk, vb);
    attn_kernel<<<dim3(64, 8, 1), dim3(256), 0, stream>>>(qk, vb);
    proj_gemm<<<dim3(16, 4, NB), dim3(256), 0, stream>>>(qk, wp, bp, xb16, out);
}

// Round 6
// 148.702 us; speedup vs baseline: 1.3056x; 1.0079x over previous
//
#include <hip/hip_runtime.h>
#include <math.h>

#define NB 8
#define CH 512
#define NTOK 1024

typedef short          bf16x8 __attribute__((ext_vector_type(8)));
typedef unsigned short u16x8  __attribute__((ext_vector_type(8)));
typedef unsigned short u16x4  __attribute__((ext_vector_type(4)));
typedef unsigned short u16x2  __attribute__((ext_vector_type(2)));
typedef float          f32x4  __attribute__((ext_vector_type(4)));
typedef unsigned int   u32x2  __attribute__((ext_vector_type(2)));

__device__ __forceinline__ float bf2f(unsigned short u) {
    unsigned int x = ((unsigned int)u) << 16;
    return __builtin_bit_cast(float, x);
}
__device__ __forceinline__ unsigned short f2bf(float f) {
    unsigned int x = __builtin_bit_cast(unsigned int, f);
    x += 0x7fff + ((x >> 16) & 1);   // RNE
    return (unsigned short)(x >> 16);
}
// truncating pack of two f32 -> two bf16 (P only; common-mode cancels in O = sum(PV)/sum(P))
__device__ __forceinline__ unsigned int pack_trunc(float a, float b) {
    unsigned int ua = __builtin_bit_cast(unsigned int, a);
    unsigned int ub = __builtin_bit_cast(unsigned int, b);
    return (ua >> 16) | (ub & 0xFFFF0000u);
}

// async global->LDS, 16B per lane; LDS dest = base + lane*16 (wave-uniform base)
__device__ __forceinline__ void async16(const void* g, void* l) {
    __builtin_amdgcn_global_load_lds(
        (const __attribute__((address_space(1))) unsigned int*)g,
        (__attribute__((address_space(3))) unsigned int*)l, 16, 0, 0);
}

// ---- prep: blocks 0..255 = (b,group): GN stats + xb16 copy + GN-apply + transpose
//      blocks 256+ = weight fp32->bf16 conversion ----
__global__ __launch_bounds__(256) void prep_kernel(
    const float* __restrict__ x,
    unsigned short* __restrict__ xb16,
    const float* __restrict__ gw, const float* __restrict__ gb,
    const float* __restrict__ qkv_w, const float* __restrict__ qkv_b,
    const float* __restrict__ proj_w, const float* __restrict__ proj_b,
    unsigned short* __restrict__ wq, unsigned short* __restrict__ bq,
    unsigned short* __restrict__ wp, unsigned short* __restrict__ bp,
    unsigned short* __restrict__ xn)
{
    __shared__ float red[8];
    __shared__ float mr[2];
    int bx = blockIdx.x;
    int t = threadIdx.x;
    if (bx >= 256) {
        int i = (bx - 256) * 256 + t;
        if (i < 786432) wq[i] = f2bf(qkv_w[i]);
        else if (i < 787968) bq[i - 786432] = f2bf(qkv_b[i - 786432]);
        else if (i < 1050112) wp[i - 787968] = f2bf(proj_w[i - 787968]);
        else if (i < 1050624) bp[i - 1050112] = f2bf(proj_b[i - 1050112]);
        return;
    }
    int b = bx >> 5, g = bx & 31, c0 = g * 16;
    const f32x4* p = (const f32x4*)(x + (size_t)bx * 16384);
    u16x4* xb4 = (u16x4*)(xb16 + (size_t)bx * 16384);

    u16x2 hold[16][2];
    float s = 0.f, sq = 0.f;
    #pragma unroll
    for (int k = 0; k < 16; ++k) {
        f32x4 v = p[t + k * 256];
        u16x4 o;
        #pragma unroll
        for (int j = 0; j < 4; ++j) {
            s += v[j]; sq += v[j] * v[j];
            o[j] = f2bf(v[j]);
        }
        hold[k][0] = (u16x2){o[0], o[1]};
        hold[k][1] = (u16x2){o[2], o[3]};
        xb4[t + k * 256] = o;
    }
    for (int off = 32; off > 0; off >>= 1) {
        s  += __shfl_down(s, off);
        sq += __shfl_down(sq, off);
    }
    int lane = t & 63, wv = t >> 6;
    if (lane == 0) { red[wv] = s; red[wv + 4] = sq; }
    __syncthreads();
    if (t == 0) {
        float ts = red[0] + red[1] + red[2] + red[3];
        float tq = red[4] + red[5] + red[6] + red[7];
        float mean = ts * (1.f / 16384.f);
        float var  = tq * (1.f / 16384.f) - mean * mean;
        mr[0] = mean;
        mr[1] = rsqrtf(fmaxf(var, 0.f) + 1e-6f);
    }
    __syncthreads();
    float mean = mr[0], rstd = mr[1];

    float scale[16], shift[16];
    #pragma unroll
    for (int c = 0; c < 16; ++c) {
        scale[c] = rstd * gw[c0 + c];
        shift[c] = gb[c0 + c] - mean * scale[c];
    }
    #pragma unroll
    for (int j = 0; j < 4; ++j) {
        u16x8 r0, r1;
        #pragma unroll
        for (int c = 0; c < 8; ++c) {
            r0[c] = f2bf(bf2f(hold[c][j >> 1][j & 1]) * scale[c] + shift[c]);
            r1[c] = f2bf(bf2f(hold[c + 8][j >> 1][j & 1]) * scale[c + 8] + shift[c + 8]);
        }
        unsigned short* orow = xn + ((size_t)(b * NTOK + 4 * t + j)) * CH + c0;
        *(u16x8*)orow       = r0;
        *(u16x8*)(orow + 8) = r1;
    }
}

// ======== QKV GEMM: 128 tok x 128 out, BK=64, 2-phase double-buffered ========
__global__ __launch_bounds__(256) void qkv_gemm(
    const unsigned short* __restrict__ xn,   // [b][1024][512]
    const unsigned short* __restrict__ wq,   // [1536][512]
    const unsigned short* __restrict__ bq,   // [1536]
    unsigned short* __restrict__ qk,         // [b][1024][1024]
    unsigned short* __restrict__ vb)         // [b*8+h][64][1024]
{
    __shared__ __align__(16) unsigned short Ash[2][128 * 64];   // 2 x 16 KB
    __shared__ __align__(16) unsigned short Wsh[2][128 * 64];   // 2 x 16 KB
    int n0 = blockIdx.x * 128, o0 = blockIdx.y * 128, b = blockIdx.z;
    int t = threadIdx.x, L = t & 63, wv = t >> 6, l15 = L & 15, qd = L >> 4;
    int to0 = (wv & 1) * 64, wo0 = (wv >> 1) * 64;
    int srow = L >> 3;                 // row-within-8 for staging
    int schunk = (L & 7) ^ srow;       // pre-swizzled 16B chunk (0..7)

    f32x4 acc[4][4];
    #pragma unroll
    for (int i = 0; i < 4; ++i)
        #pragma unroll
        for (int j = 0; j < 4; ++j) acc[i][j] = (f32x4){0.f, 0.f, 0.f, 0.f};

    // stage one BK=64 tile into buffer nb: A 16 KB + W 16 KB (8 async16/thread)
    #define QSTAGE(nb, ks)                                                       \
        _Pragma("unroll")                                                        \
        for (int j = 0; j < 4; ++j) {                                            \
            int row = wv * 32 + j * 8 + srow;                                    \
            async16(xn + ((size_t)(b * NTOK + n0 + row)) * CH + (ks) * 64 + schunk * 8, \
                    &Ash[nb][(wv * 32 + j * 8) * 64]);                           \
            async16(wq + ((size_t)(o0 + row)) * CH + (ks) * 64 + schunk * 8,     \
                    &Wsh[nb][(wv * 32 + j * 8) * 64]);                           \
        }

    // consume buffer nb (64 k-depth = 2 cc chunks, 32 MFMA)
    #define QCOMP(nb)                                                            \
        _Pragma("unroll")                                                        \
        for (int cc = 0; cc < 2; ++cc) {                                         \
            int kx = ((cc * 4 + qd) ^ (l15 & 7)) * 8;                            \
            bf16x8 af[4], bfr[4];                                                \
            _Pragma("unroll")                                                    \
            for (int mi = 0; mi < 4; ++mi)                                       \
                af[mi] = *(const bf16x8*)&Ash[nb][(to0 + mi * 16 + l15) * 64 + kx]; \
            _Pragma("unroll")                                                    \
            for (int ni = 0; ni < 4; ++ni)                                       \
                bfr[ni] = *(const bf16x8*)&Wsh[nb][(wo0 + ni * 16 + l15) * 64 + kx]; \
            _Pragma("unroll")                                                    \
            for (int mi = 0; mi < 4; ++mi)                                       \
                _Pragma("unroll")                                                \
                for (int ni = 0; ni < 4; ++ni)                                   \
                    acc[mi][ni] = __builtin_amdgcn_mfma_f32_16x16x32_bf16(       \
                        af[mi], bfr[ni], acc[mi][ni], 0, 0, 0);                  \
        }

    QSTAGE(0, 0)
    #pragma unroll 1
    for (int ks = 0; ks < 8; ks += 2) {
        __syncthreads();                 // buf0 (chunk ks) ready; buf1 free
        QSTAGE(1, ks + 1)
        QCOMP(0)
        __syncthreads();                 // buf1 ready; buf0 free
        if (ks < 6) { QSTAGE(0, ks + 2) }
        QCOMP(1)
    }
    #undef QSTAGE
    #undef QCOMP

    if (o0 < 1024) {
        #pragma unroll
        for (int ni = 0; ni < 4; ++ni) {
            int o = o0 + wo0 + ni * 16 + l15;
            float bias = bf2f(bq[o]);
            #pragma unroll
            for (int mi = 0; mi < 4; ++mi) {
                int tok = n0 + to0 + mi * 16 + qd * 4;
                #pragma unroll
                for (int r = 0; r < 4; ++r)
                    qk[((size_t)b * NTOK + tok + r) * 1024 + o] = f2bf(acc[mi][ni][r] + bias);
            }
        }
    } else {
        #pragma unroll
        for (int ni = 0; ni < 4; ++ni) {
            int oo = o0 - 1024 + wo0 + ni * 16 + l15;
            int h = oo >> 6, c = oo & 63;
            float bias = bf2f(bq[1024 + oo]);
            #pragma unroll
            for (int mi = 0; mi < 4; ++mi) {
                int tok = n0 + to0 + mi * 16 + qd * 4;
                u16x4 pk;
                #pragma unroll
                for (int r = 0; r < 4; ++r) pk[r] = f2bf(acc[mi][ni][r] + bias);
                *(u16x4*)&vb[((size_t)(b * 8 + h) * 64 + c) * NTOK + tok] = pk;
            }
        }
    }
}

// ====== proj GEMM: 64 tok x 128 out, BK=64, 2-phase double-buffered ======
__global__ __launch_bounds__(256) void proj_gemm(
    const unsigned short* __restrict__ ao,   // qk: cols [0,512) attn out, pitch 1024
    const unsigned short* __restrict__ wp,   // [512][512]
    const unsigned short* __restrict__ bp,   // [512]
    const unsigned short* __restrict__ xb16, // residual bf16 [b][512][1024]
    float* __restrict__ out)                 // [b][512][1024]
{
    __shared__ __align__(16) unsigned short Ash[2][64 * 64];    // 2 x 8 KB
    __shared__ __align__(16) unsigned short Wsh[2][128 * 64];   // 2 x 16 KB
    int n0 = blockIdx.x * 64, o0 = blockIdx.y * 128, b = blockIdx.z;
    int t = threadIdx.x, L = t & 63, wv = t >> 6, l15 = L & 15, qd = L >> 4;
    int to0 = (wv & 1) * 32, wo0 = (wv >> 1) * 64;
    int srow = L >> 3;
    int schunk = (L & 7) ^ srow;

    f32x4 acc[2][4];
    #pragma unroll
    for (int i = 0; i < 2; ++i)
        #pragma unroll
        for (int j = 0; j < 4; ++j) acc[i][j] = (f32x4){0.f, 0.f, 0.f, 0.f};

    #define PSTAGE(nb, ks)                                                       \
        _Pragma("unroll")                                                        \
        for (int j = 0; j < 2; ++j) {                                            \
            int row = wv * 16 + j * 8 + srow;                                    \
            async16(ao + ((size_t)(b * NTOK + n0 + row)) * 1024 + (ks) * 64 + schunk * 8, \
                    &Ash[nb][(wv * 16 + j * 8) * 64]);                           \
        }                                                                        \
        _Pragma("unroll")                                                        \
        for (int j = 0; j < 4; ++j) {                                            \
            int row = wv * 32 + j * 8 + srow;                                    \
            async16(wp + ((size_t)(o0 + row)) * CH + (ks) * 64 + schunk * 8,     \
                    &Wsh[nb][(wv * 32 + j * 8) * 64]);                           \
        }

    #define PCOMP(nb)                                                            \
        _Pragma("unroll")                                                        \
        for (int cc = 0; cc < 2; ++cc) {                                         \
            int kx = ((cc * 4 + qd) ^ (l15 & 7)) * 8;                            \
            bf16x8 af[2], bfr[4];                                                \
            _Pragma("unroll")                                                    \
            for (int mi = 0; mi < 2; ++mi)                                       \
                af[mi] = *(const bf16x8*)&Ash[nb][(to0 + mi * 16 + l15) * 64 + kx]; \
            _Pragma("unroll")                                                    \
            for (int ni = 0; ni < 4; ++ni)                                       \
                bfr[ni] = *(const bf16x8*)&Wsh[nb][(wo0 + ni * 16 + l15) * 64 + kx]; \
            _Pragma("unroll")                                                    \
            for (int mi = 0; mi < 2; ++mi)                                       \
                _Pragma("unroll")                                                \
                for (int ni = 0; ni < 4; ++ni)                                   \
                    acc[mi][ni] = __builtin_amdgcn_mfma_f32_16x16x32_bf16(       \
                        af[mi], bfr[ni], acc[mi][ni], 0, 0, 0);                  \
        }

    PSTAGE(0, 0)
    #pragma unroll 1
    for (int ks = 0; ks < 8; ks += 2) {
        __syncthreads();
        PSTAGE(1, ks + 1)
        PCOMP(0)
        __syncthreads();
        if (ks < 6) { PSTAGE(0, ks + 2) }
        PCOMP(1)
    }
    #undef PSTAGE
    #undef PCOMP

    #pragma unroll
    for (int ni = 0; ni < 4; ++ni) {
        int o = o0 + wo0 + ni * 16 + l15;
        float bias = bf2f(bp[o]);
        #pragma unroll
        for (int mi = 0; mi < 2; ++mi) {
            int tok = n0 + to0 + mi * 16 + qd * 4;
            size_t base = ((size_t)(b * CH + o)) * NTOK + tok;
            u16x4 res = *(const u16x4*)(xb16 + base);
            f32x4 vv;
            #pragma unroll
            for (int r = 0; r < 4; ++r) vv[r] = acc[mi][ni][r] + bias + bf2f(res[r]);
            *(f32x4*)(out + base) = vv;
        }
    }
}

// ===== MFMA flash attention: 128-key double buffer, 1 barrier per 128 keys =====
// LDS: Kt 32KB + Vt 32KB + Psc 16KB = 80KB -> 2 blocks/CU (matches grid 512/256CU)
__global__ __launch_bounds__(256) void attn_kernel(
    unsigned short* __restrict__ qk, const unsigned short* __restrict__ vb)
{
    __shared__ __align__(16) unsigned short Kt[2][2][64 * 64];  // [buf][half]
    __shared__ __align__(16) unsigned short Vt[2][2][64 * 64];
    __shared__ __align__(16) unsigned short Psc[4][32 * 64];    // per-wave P scratch

    int bh = blockIdx.x, b = bh >> 3, h = bh & 7;
    int q0 = blockIdx.y * 128;
    int t = threadIdx.x, L = t & 63, wv = t >> 6, l15 = L & 15, qd = L >> 4;
    int srow = L >> 3;
    int scol = ((L & 7) ^ srow) * 8;
    int key8 = (l15 & 7) * 8;

    const unsigned short* qkb = qk + (size_t)b * NTOK * 1024;
    const unsigned short* vbase = vb + (size_t)bh * 64 * NTOK;

    const float QSC = 0.125f * 1.44269504f;
    bf16x8 qf[2][2];
    #pragma unroll
    for (int nt = 0; nt < 2; ++nt)
        #pragma unroll
        for (int cc = 0; cc < 2; ++cc) {
            const unsigned short* qrow =
                qkb + (size_t)(q0 + wv * 32 + nt * 16 + l15) * 1024 + h * 64 + cc * 32 + qd * 8;
            u16x8 u = *(const u16x8*)qrow;
            bf16x8 s;
            #pragma unroll
            for (int j = 0; j < 8; ++j) s[j] = (short)f2bf(bf2f(u[j]) * QSC);
            qf[nt][cc] = s;
        }

    f32x4 Oacc[2][4];
    #pragma unroll
    for (int i = 0; i < 2; ++i)
        #pragma unroll
        for (int j = 0; j < 4; ++j) Oacc[i][j] = (f32x4){0.f, 0.f, 0.f, 0.f};
    float lsum[2] = {0.f, 0.f};

    // stage a 128-key tile (both halves: K 16KB + V 16KB, 8 async16/thread) into buffer nb
    #define ASTAGE(nb, m0)                                                           \
        _Pragma("unroll")                                                            \
        for (int sj = 0; sj < 2; ++sj)                                               \
            _Pragma("unroll")                                                        \
            for (int j = 0; j < 2; ++j) {                                            \
                int is = wv * 2 + j;                                                 \
                async16(qkb + (size_t)((m0) + sj * 64 + is * 8 + srow) * 1024 + 512 + h * 64 + scol, \
                        &Kt[nb][sj][is * 512]);                                      \
                async16(vbase + (size_t)(is * 8 + srow) * 1024 + (m0) + sj * 64 + scol, \
                        &Vt[nb][sj][is * 512]);                                      \
            }

    // consume one 64-key half: QK^T (16 MFMA) + exp/pack + PV (16 MFMA)
    #define ACOMP(nb, sj)                                                            \
    {                                                                                \
        f32x4 st[4][2];                                                              \
        _Pragma("unroll")                                                            \
        for (int mt = 0; mt < 4; ++mt)                                               \
            _Pragma("unroll")                                                        \
            for (int nt = 0; nt < 2; ++nt) st[mt][nt] = (f32x4){0.f, 0.f, 0.f, 0.f}; \
        _Pragma("unroll")                                                            \
        for (int cc = 0; cc < 2; ++cc) {                                             \
            _Pragma("unroll")                                                        \
            for (int mt = 0; mt < 4; ++mt) {                                         \
                bf16x8 a = *(const bf16x8*)&Kt[nb][sj][(mt * 16 + l15) * 64 + ((cc * 32 + qd * 8) ^ key8)]; \
                _Pragma("unroll")                                                    \
                for (int nt = 0; nt < 2; ++nt)                                       \
                    st[mt][nt] = __builtin_amdgcn_mfma_f32_16x16x32_bf16(a, qf[nt][cc], st[mt][nt], 0, 0, 0); \
            }                                                                        \
        }                                                                            \
        _Pragma("unroll")                                                            \
        for (int mt = 0; mt < 4; ++mt)                                               \
            _Pragma("unroll")                                                        \
            for (int nt = 0; nt < 2; ++nt) {                                         \
                float p0 = __builtin_amdgcn_exp2f(st[mt][nt][0]);                    \
                float p1 = __builtin_amdgcn_exp2f(st[mt][nt][1]);                    \
                float p2 = __builtin_amdgcn_exp2f(st[mt][nt][2]);                    \
                float p3 = __builtin_amdgcn_exp2f(st[mt][nt][3]);                    \
                lsum[nt] += (p0 + p1) + (p2 + p3);                                   \
                u32x2 pw = { pack_trunc(p0, p1), pack_trunc(p2, p3) };               \
                *(u32x2*)&Psc[wv][(nt * 16 + l15) * 64 + ((mt * 16 + 4 * qd) ^ key8)] = pw; \
            }                                                                        \
        _Pragma("unroll")                                                            \
        for (int mk = 0; mk < 2; ++mk) {                                             \
            bf16x8 ap[2];                                                            \
            _Pragma("unroll")                                                        \
            for (int nt = 0; nt < 2; ++nt)                                           \
                ap[nt] = *(const bf16x8*)&Psc[wv][(nt * 16 + l15) * 64 + ((mk * 32 + qd * 8) ^ key8)]; \
            _Pragma("unroll")                                                        \
            for (int ct = 0; ct < 4; ++ct) {                                         \
                bf16x8 bv = *(const bf16x8*)&Vt[nb][sj][(ct * 16 + l15) * 64 + ((mk * 32 + qd * 8) ^ key8)]; \
                _Pragma("unroll")                                                    \
                for (int nt = 0; nt < 2; ++nt)                                       \
                    Oacc[nt][ct] = __builtin_amdgcn_mfma_f32_16x16x32_bf16(ap[nt], bv, Oacc[nt][ct], 0, 0, 0); \
            }                                                                        \
        }                                                                            \
    }

    ASTAGE(0, 0)
    #pragma unroll 1
    for (int m0 = 0; m0 < NTOK; m0 += 256) {
        __syncthreads();                    // buf0 (keys m0..m0+127) ready; buf1 free
        ASTAGE(1, m0 + 128)                 // prefetch next 128 keys (m0+128 <= 896 always)
        ACOMP(0, 0) ACOMP(0, 1)             // both halves in one barrier region (ILP)
        __syncthreads();                    // buf1 ready; buf0 free
        if (m0 + 256 < NTOK) { ASTAGE(0, m0 + 256) }
        ACOMP(1, 0) ACOMP(1, 1)
    }
    #undef ASTAGE
    #undef ACOMP

    #pragma unroll
    for (int nt = 0; nt < 2; ++nt) {
        lsum[nt] += __shfl_xor(lsum[nt], 16);
        lsum[nt] += __shfl_xor(lsum[nt], 32);
        float inv = 1.f / lsum[nt];
        #pragma unroll
        for (int r = 0; r < 4; ++r) {
            float ir = __shfl(inv, 4 * qd + r);
            int n = q0 + wv * 32 + nt * 16 + qd * 4 + r;
            unsigned short* orow = qk + ((size_t)b * NTOK + n) * 1024 + h * 64;
            #pragma unroll
            for (int ct = 0; ct < 4; ++ct)
                orow[ct * 16 + l15] = f2bf(Oacc[nt][ct][r] * ir);
        }
    }
}

extern "C" void kernel_launch(void* const* d_in, const int* in_sizes, int n_in,
                              void* d_out, int out_size, void* d_ws, size_t ws_size,
                              hipStream_t stream) {
    const float* x      = (const float*)d_in[0];
    const float* norm_w = (const float*)d_in[1];
    const float* norm_b = (const float*)d_in[2];
    const float* qkv_w  = (const float*)d_in[3];
    const float* qkv_b  = (const float*)d_in[4];
    const float* proj_w = (const float*)d_in[5];
    const float* proj_b = (const float*)d_in[6];
    float* out = (float*)d_out;

    // ws: qk 16MB | vb 8MB | wp 512KB | bp 1KB | pad | xb16 16MB
    const size_t QK_B = (size_t)NB * NTOK * 1024 * 2;        // 16,777,216
    const size_t VB_B = (size_t)NB * 8 * 64 * NTOK * 2;      //  8,388,608
    const size_t XB_OFF = QK_B + VB_B + 1048576;
    if (ws_size < XB_OFF + (size_t)NB * CH * NTOK * 2) return;
    unsigned short* qk = (unsigned short*)d_ws;
    unsigned short* vb = (unsigned short*)((char*)d_ws + QK_B);
    unsigned short* wp = (unsigned short*)((char*)d_ws + QK_B + VB_B);
    unsigned short* bp = (unsigned short*)((char*)d_ws + QK_B + VB_B + 524288);
    unsigned short* xb16 = (unsigned short*)((char*)d_ws + XB_OFF);

    // d_out scratch (dead until proj writes): xn 8 MB | wq 1.5 MB | bq 3 KB
    unsigned short* xn = (unsigned short*)d_out;
    unsigned short* wq = (unsigned short*)((char*)d_out + 8388608);
    unsigned short* bq = (unsigned short*)((char*)d_out + 9961472);

    prep_kernel<<<dim3(4361), dim3(256), 0, stream>>>(
        x, xb16, norm_w, norm_b, qkv_w, qkv_b, proj_w, proj_b, wq, bq, wp, bp, xn);
    qkv_gemm<<<dim3(8, 12, NB), dim3(256), 0, stream>>>(xn, wq, bq, qk, vb);
    attn_kernel<<<dim3(64, 8, 1), dim3(256), 0, stream>>>(qk, vb);
    proj_gemm<<<dim3(16, 4, NB), dim3(256), 0, stream>>>(qk, wp, bp, xb16, out);
}

// Round 11
// 147.413 us; speedup vs baseline: 1.3170x; 1.0087x over previous
//
#include <hip/hip_runtime.h>
#include <math.h>

#define NB 8
#define CH 512
#define NTOK 1024

typedef short          bf16x8 __attribute__((ext_vector_type(8)));
typedef unsigned short u16x8  __attribute__((ext_vector_type(8)));
typedef unsigned short u16x4  __attribute__((ext_vector_type(4)));
typedef unsigned short u16x2  __attribute__((ext_vector_type(2)));
typedef float          f32x4  __attribute__((ext_vector_type(4)));
typedef unsigned int   u32x2  __attribute__((ext_vector_type(2)));

__device__ __forceinline__ float bf2f(unsigned short u) {
    unsigned int x = ((unsigned int)u) << 16;
    return __builtin_bit_cast(float, x);
}
__device__ __forceinline__ unsigned short f2bf(float f) {
    unsigned int x = __builtin_bit_cast(unsigned int, f);
    x += 0x7fff + ((x >> 16) & 1);   // RNE
    return (unsigned short)(x >> 16);
}
// truncating pack of two f32 -> two bf16 (P only; common-mode cancels in O = sum(PV)/sum(P))
__device__ __forceinline__ unsigned int pack_trunc(float a, float b) {
    unsigned int ua = __builtin_bit_cast(unsigned int, a);
    unsigned int ub = __builtin_bit_cast(unsigned int, b);
    return (ua >> 16) | (ub & 0xFFFF0000u);
}

// async global->LDS, 16B per lane; LDS dest = base + lane*16 (wave-uniform base)
__device__ __forceinline__ void async16(const void* g, void* l) {
    __builtin_amdgcn_global_load_lds(
        (const __attribute__((address_space(1))) unsigned int*)g,
        (__attribute__((address_space(3))) unsigned int*)l, 16, 0, 0);
}

// ---- prep: blocks 0..255 = (b,group): GN stats + xb16 copy + GN-apply + transpose
//      blocks 256+ = weight fp32->bf16 conversion ----
__global__ __launch_bounds__(256) void prep_kernel(
    const float* __restrict__ x,
    unsigned short* __restrict__ xb16,
    const float* __restrict__ gw, const float* __restrict__ gb,
    const float* __restrict__ qkv_w, const float* __restrict__ qkv_b,
    const float* __restrict__ proj_w, const float* __restrict__ proj_b,
    unsigned short* __restrict__ wq, unsigned short* __restrict__ bq,
    unsigned short* __restrict__ wp, unsigned short* __restrict__ bp,
    unsigned short* __restrict__ xn)
{
    __shared__ float red[8];
    __shared__ float mr[2];
    int bx = blockIdx.x;
    int t = threadIdx.x;
    if (bx >= 256) {
        int i = (bx - 256) * 256 + t;
        if (i < 786432) wq[i] = f2bf(qkv_w[i]);
        else if (i < 787968) bq[i - 786432] = f2bf(qkv_b[i - 786432]);
        else if (i < 1050112) wp[i - 787968] = f2bf(proj_w[i - 787968]);
        else if (i < 1050624) bp[i - 1050112] = f2bf(proj_b[i - 1050112]);
        return;
    }
    int b = bx >> 5, g = bx & 31, c0 = g * 16;
    const f32x4* p = (const f32x4*)(x + (size_t)bx * 16384);
    u16x4* xb4 = (u16x4*)(xb16 + (size_t)bx * 16384);

    u16x2 hold[16][2];
    float s = 0.f, sq = 0.f;
    #pragma unroll
    for (int k = 0; k < 16; ++k) {
        f32x4 v = p[t + k * 256];
        u16x4 o;
        #pragma unroll
        for (int j = 0; j < 4; ++j) {
            s += v[j]; sq += v[j] * v[j];
            o[j] = f2bf(v[j]);
        }
        hold[k][0] = (u16x2){o[0], o[1]};
        hold[k][1] = (u16x2){o[2], o[3]};
        xb4[t + k * 256] = o;
    }
    for (int off = 32; off > 0; off >>= 1) {
        s  += __shfl_down(s, off);
        sq += __shfl_down(sq, off);
    }
    int lane = t & 63, wv = t >> 6;
    if (lane == 0) { red[wv] = s; red[wv + 4] = sq; }
    __syncthreads();
    if (t == 0) {
        float ts = red[0] + red[1] + red[2] + red[3];
        float tq = red[4] + red[5] + red[6] + red[7];
        float mean = ts * (1.f / 16384.f);
        float var  = tq * (1.f / 16384.f) - mean * mean;
        mr[0] = mean;
        mr[1] = rsqrtf(fmaxf(var, 0.f) + 1e-6f);
    }
    __syncthreads();
    float mean = mr[0], rstd = mr[1];

    float scale[16], shift[16];
    #pragma unroll
    for (int c = 0; c < 16; ++c) {
        scale[c] = rstd * gw[c0 + c];
        shift[c] = gb[c0 + c] - mean * scale[c];
    }
    #pragma unroll
    for (int j = 0; j < 4; ++j) {
        u16x8 r0, r1;
        #pragma unroll
        for (int c = 0; c < 8; ++c) {
            r0[c] = f2bf(bf2f(hold[c][j >> 1][j & 1]) * scale[c] + shift[c]);
            r1[c] = f2bf(bf2f(hold[c + 8][j >> 1][j & 1]) * scale[c + 8] + shift[c + 8]);
        }
        unsigned short* orow = xn + ((size_t)(b * NTOK + 4 * t + j)) * CH + c0;
        *(u16x8*)orow       = r0;
        *(u16x8*)(orow + 8) = r1;
    }
}

// ======== QKV GEMM: 128 tok x 128 out, BK=64, 2-phase + coalesced epilogue ========
__global__ __launch_bounds__(256) void qkv_gemm(
    const unsigned short* __restrict__ xn,   // [b][1024][512]
    const unsigned short* __restrict__ wq,   // [1536][512]
    const unsigned short* __restrict__ bq,   // [1536]
    unsigned short* __restrict__ qk,         // [b][1024][1024]
    unsigned short* __restrict__ vb)         // [b*8+h][64][1024]
{
    __shared__ __align__(16) unsigned short SMp[32768];   // 64 KB pool
    #define QA(nb) (SMp + (nb) * 8192)
    #define QW(nb) (SMp + 16384 + (nb) * 8192)
    int n0 = blockIdx.x * 128, o0 = blockIdx.y * 128, b = blockIdx.z;
    int t = threadIdx.x, L = t & 63, wv = t >> 6, l15 = L & 15, qd = L >> 4;
    int to0 = (wv & 1) * 64, wo0 = (wv >> 1) * 64;
    int srow = L >> 3;                 // row-within-8 for staging
    int schunk = (L & 7) ^ srow;       // pre-swizzled 16B chunk (0..7)

    f32x4 acc[4][4];
    #pragma unroll
    for (int i = 0; i < 4; ++i)
        #pragma unroll
        for (int j = 0; j < 4; ++j) acc[i][j] = (f32x4){0.f, 0.f, 0.f, 0.f};

    #define QSTAGE(nb, ks)                                                       \
        _Pragma("unroll")                                                        \
        for (int j = 0; j < 4; ++j) {                                            \
            int row = wv * 32 + j * 8 + srow;                                    \
            async16(xn + ((size_t)(b * NTOK + n0 + row)) * CH + (ks) * 64 + schunk * 8, \
                    &QA(nb)[(wv * 32 + j * 8) * 64]);                            \
            async16(wq + ((size_t)(o0 + row)) * CH + (ks) * 64 + schunk * 8,     \
                    &QW(nb)[(wv * 32 + j * 8) * 64]);                            \
        }

    #define QCOMP(nb)                                                            \
        _Pragma("unroll")                                                        \
        for (int cc = 0; cc < 2; ++cc) {                                         \
            int kx = ((cc * 4 + qd) ^ (l15 & 7)) * 8;                            \
            bf16x8 af[4], bfr[4];                                                \
            _Pragma("unroll")                                                    \
            for (int mi = 0; mi < 4; ++mi)                                       \
                af[mi] = *(const bf16x8*)&QA(nb)[(to0 + mi * 16 + l15) * 64 + kx]; \
            _Pragma("unroll")                                                    \
            for (int ni = 0; ni < 4; ++ni)                                       \
                bfr[ni] = *(const bf16x8*)&QW(nb)[(wo0 + ni * 16 + l15) * 64 + kx]; \
            _Pragma("unroll")                                                    \
            for (int mi = 0; mi < 4; ++mi)                                       \
                _Pragma("unroll")                                                \
                for (int ni = 0; ni < 4; ++ni)                                   \
                    acc[mi][ni] = __builtin_amdgcn_mfma_f32_16x16x32_bf16(       \
                        af[mi], bfr[ni], acc[mi][ni], 0, 0, 0);                  \
        }

    QSTAGE(0, 0)
    #pragma unroll 1
    for (int ks = 0; ks < 8; ks += 2) {
        __syncthreads();                 // buf0 (chunk ks) ready; buf1 free
        QSTAGE(1, ks + 1)
        QCOMP(0)
        __syncthreads();                 // buf1 ready; buf0 free
        if (ks < 6) { QSTAGE(0, ks + 2) }
        QCOMP(1)
    }
    #undef QSTAGE
    #undef QCOMP

    // ---- coalesced epilogue via LDS transpose (reuse staging pool) ----
    __syncthreads();                     // all waves done reading QA/QW
    if (o0 < 1024) {
        // stage [tok 128][136-pad] bf16 (34 KB <= 64 KB pool)
        #pragma unroll
        for (int ni = 0; ni < 4; ++ni) {
            float bias = bf2f(bq[o0 + wo0 + ni * 16 + l15]);
            #pragma unroll
            for (int mi = 0; mi < 4; ++mi) {
                int tk = to0 + mi * 16 + qd * 4;
                #pragma unroll
                for (int r = 0; r < 4; ++r)
                    SMp[(tk + r) * 136 + wo0 + ni * 16 + l15] = f2bf(acc[mi][ni][r] + bias);
            }
        }
        __syncthreads();
        int row = t >> 1, half = t & 1;                       // 128 rows x 2 halves of 64
        const unsigned short* src = &SMp[row * 136 + half * 64];
        unsigned short* dst = qk + ((size_t)(b * NTOK + n0 + row)) * 1024 + o0 + half * 64;
        #pragma unroll
        for (int i = 0; i < 8; ++i)                           // 8 x 16B = 128B/thread
            *(u16x8*)(dst + i * 8) = *(const u16x8*)(src + i * 8);
    } else {
        // stage [ch 128][136-pad] bf16 -> vb rows are tok-contiguous
        #pragma unroll
        for (int ni = 0; ni < 4; ++ni) {
            int ol = wo0 + ni * 16 + l15;
            float bias = bf2f(bq[o0 + ol]);
            #pragma unroll
            for (int mi = 0; mi < 4; ++mi) {
                u16x4 pk;
                #pragma unroll
                for (int r = 0; r < 4; ++r) pk[r] = f2bf(acc[mi][ni][r] + bias);
                *(u16x4*)&SMp[ol * 136 + to0 + mi * 16 + qd * 4] = pk;
            }
        }
        __syncthreads();
        int c = t >> 1, half = t & 1;
        int oo = o0 - 1024 + c; int hh = oo >> 6, cl = oo & 63;
        const unsigned short* src = &SMp[c * 136 + half * 64];
        unsigned short* dst = vb + ((size_t)(b * 8 + hh) * 64 + cl) * 1024 + n0 + half * 64;
        #pragma unroll
        for (int i = 0; i < 8; ++i)                           // 8 x 16B = 128B/thread
            *(u16x8*)(dst + i * 8) = *(const u16x8*)(src + i * 8);
    }
    #undef QA
    #undef QW
}

// ====== proj GEMM: 64 tok x 128 out, BK=64, 2-phase + coalesced epilogue ======
__global__ __launch_bounds__(256) void proj_gemm(
    const unsigned short* __restrict__ ao,   // qk: cols [0,512) attn out, pitch 1024
    const unsigned short* __restrict__ wp,   // [512][512]
    const unsigned short* __restrict__ bp,   // [512]
    const unsigned short* __restrict__ xb16, // residual bf16 [b][512][1024]
    float* __restrict__ out)                 // [b][512][1024]
{
    __shared__ __align__(16) unsigned char PM[49152];     // 48 KB pool
    unsigned short* PA = (unsigned short*)PM;             // 2 x 64*64
    unsigned short* PW = (unsigned short*)(PM + 16384);   // 2 x 128*64
    #define PAb(nb) (PA + (nb) * 4096)
    #define PWb(nb) (PW + (nb) * 8192)
    int n0 = blockIdx.x * 64, o0 = blockIdx.y * 128, b = blockIdx.z;
    int t = threadIdx.x, L = t & 63, wv = t >> 6, l15 = L & 15, qd = L >> 4;
    int to0 = (wv & 1) * 32, wo0 = (wv >> 1) * 64;
    int srow = L >> 3;
    int schunk = (L & 7) ^ srow;

    f32x4 acc[2][4];
    #pragma unroll
    for (int i = 0; i < 2; ++i)
        #pragma unroll
        for (int j = 0; j < 4; ++j) acc[i][j] = (f32x4){0.f, 0.f, 0.f, 0.f};

    #define PSTAGE(nb, ks)                                                       \
        _Pragma("unroll")                                                        \
        for (int j = 0; j < 2; ++j) {                                            \
            int row = wv * 16 + j * 8 + srow;                                    \
            async16(ao + ((size_t)(b * NTOK + n0 + row)) * 1024 + (ks) * 64 + schunk * 8, \
                    &PAb(nb)[(wv * 16 + j * 8) * 64]);                           \
        }                                                                        \
        _Pragma("unroll")                                                        \
        for (int j = 0; j < 4; ++j) {                                            \
            int row = wv * 32 + j * 8 + srow;                                    \
            async16(wp + ((size_t)(o0 + row)) * CH + (ks) * 64 + schunk * 8,     \
                    &PWb(nb)[(wv * 32 + j * 8) * 64]);                           \
        }

    #define PCOMP(nb)                                                            \
        _Pragma("unroll")                                                        \
        for (int cc = 0; cc < 2; ++cc) {                                         \
            int kx = ((cc * 4 + qd) ^ (l15 & 7)) * 8;                            \
            bf16x8 af[2], bfr[4];                                                \
            _Pragma("unroll")                                                    \
            for (int mi = 0; mi < 2; ++mi)                                       \
                af[mi] = *(const bf16x8*)&PAb(nb)[(to0 + mi * 16 + l15) * 64 + kx]; \
            _Pragma("unroll")                                                    \
            for (int ni = 0; ni < 4; ++ni)                                       \
                bfr[ni] = *(const bf16x8*)&PWb(nb)[(wo0 + ni * 16 + l15) * 64 + kx]; \
            _Pragma("unroll")                                                    \
            for (int mi = 0; mi < 2; ++mi)                                       \
                _Pragma("unroll")                                                \
                for (int ni = 0; ni < 4; ++ni)                                   \
                    acc[mi][ni] = __builtin_amdgcn_mfma_f32_16x16x32_bf16(       \
                        af[mi], bfr[ni], acc[mi][ni], 0, 0, 0);                  \
        }

    PSTAGE(0, 0)
    #pragma unroll 1
    for (int ks = 0; ks < 8; ks += 2) {
        __syncthreads();
        PSTAGE(1, ks + 1)
        PCOMP(0)
        __syncthreads();
        if (ks < 6) { PSTAGE(0, ks + 2) }
        PCOMP(1)
    }
    #undef PSTAGE
    #undef PCOMP

    // ---- coalesced epilogue: stage [ch 128][68-pad] f32, fold residual in pass 2 ----
    __syncthreads();
    float* Fst = (float*)PM;                 // 128*68*4 = 34816 B <= 48 KB
    #pragma unroll
    for (int ni = 0; ni < 4; ++ni) {
        float bias = bf2f(bp[o0 + wo0 + ni * 16 + l15]);
        #pragma unroll
        for (int mi = 0; mi < 2; ++mi) {
            f32x4 v;
            #pragma unroll
            for (int r = 0; r < 4; ++r) v[r] = acc[mi][ni][r] + bias;
            *(f32x4*)&Fst[(wo0 + ni * 16 + l15) * 68 + to0 + mi * 16 + qd * 4] = v;
        }
    }
    __syncthreads();
    int o = t >> 1, half = t & 1;            // 128 ch rows x 2 halves of 32 tok
    const float* src = &Fst[o * 68 + half * 32];
    size_t gb = ((size_t)(b * CH + o0 + o)) * 1024 + n0 + half * 32;
    const unsigned short* res = xb16 + gb;
    float* dst = out + gb;
    #pragma unroll
    for (int i = 0; i < 8; ++i) {
        u16x4 rv = *(const u16x4*)(res + i * 4);
        f32x4 v = *(const f32x4*)(src + i * 4);
        #pragma unroll
        for (int r = 0; r < 4; ++r) v[r] += bf2f(rv[r]);
        *(f32x4*)(dst + i * 4) = v;          // 128B/thread contiguous
    }
    #undef PAb
    #undef PWb
}

// ===== MFMA flash attention: 128-key double buffer + coalesced O epilogue =====
__global__ __launch_bounds__(256) void attn_kernel(
    unsigned short* __restrict__ qk, const unsigned short* __restrict__ vb)
{
    __shared__ __align__(16) unsigned short Kt[2][2][64 * 64];  // [buf][half]
    __shared__ __align__(16) unsigned short Vt[2][2][64 * 64];
    __shared__ __align__(16) unsigned short Psc[4][32 * 64];    // per-wave P scratch

    int bh = blockIdx.x, b = bh >> 3, h = bh & 7;
    int q0 = blockIdx.y * 128;
    int t = threadIdx.x, L = t & 63, wv = t >> 6, l15 = L & 15, qd = L >> 4;
    int srow = L >> 3;
    int scol = ((L & 7) ^ srow) * 8;
    int key8 = (l15 & 7) * 8;

    const unsigned short* qkb = qk + (size_t)b * NTOK * 1024;
    const unsigned short* vbase = vb + (size_t)bh * 64 * NTOK;

    const float QSC = 0.125f * 1.44269504f;
    bf16x8 qf[2][2];
    #pragma unroll
    for (int nt = 0; nt < 2; ++nt)
        #pragma unroll
        for (int cc = 0; cc < 2; ++cc) {
            const unsigned short* qrow =
                qkb + (size_t)(q0 + wv * 32 + nt * 16 + l15) * 1024 + h * 64 + cc * 32 + qd * 8;
            u16x8 u = *(const u16x8*)qrow;
            bf16x8 s;
            #pragma unroll
            for (int j = 0; j < 8; ++j) s[j] = (short)f2bf(bf2f(u[j]) * QSC);
            qf[nt][cc] = s;
        }

    f32x4 Oacc[2][4];
    #pragma unroll
    for (int i = 0; i < 2; ++i)
        #pragma unroll
        for (int j = 0; j < 4; ++j) Oacc[i][j] = (f32x4){0.f, 0.f, 0.f, 0.f};
    float lsum[2] = {0.f, 0.f};

    #define ASTAGE(nb, m0)                                                           \
        _Pragma("unroll")                                                            \
        for (int sj = 0; sj < 2; ++sj)                                               \
            _Pragma("unroll")                                                        \
            for (int j = 0; j < 2; ++j) {                                            \
                int is = wv * 2 + j;                                                 \
                async16(qkb + (size_t)((m0) + sj * 64 + is * 8 + srow) * 1024 + 512 + h * 64 + scol, \
                        &Kt[nb][sj][is * 512]);                                      \
                async16(vbase + (size_t)(is * 8 + srow) * 1024 + (m0) + sj * 64 + scol, \
                        &Vt[nb][sj][is * 512]);                                      \
            }

    #define ACOMP(nb, sj)                                                            \
    {                                                                                \
        f32x4 st[4][2];                                                              \
        _Pragma("unroll")                                                            \
        for (int mt = 0; mt < 4; ++mt)                                               \
            _Pragma("unroll")                                                        \
            for (int nt = 0; nt < 2; ++nt) st[mt][nt] = (f32x4){0.f, 0.f, 0.f, 0.f}; \
        _Pragma("unroll")                                                            \
        for (int cc = 0; cc < 2; ++cc) {                                             \
            _Pragma("unroll")                                                        \
            for (int mt = 0; mt < 4; ++mt) {                                         \
                bf16x8 a = *(const bf16x8*)&Kt[nb][sj][(mt * 16 + l15) * 64 + ((cc * 32 + qd * 8) ^ key8)]; \
                _Pragma("unroll")                                                    \
                for (int nt = 0; nt < 2; ++nt)                                       \
                    st[mt][nt] = __builtin_amdgcn_mfma_f32_16x16x32_bf16(a, qf[nt][cc], st[mt][nt], 0, 0, 0); \
            }                                                                        \
        }                                                                            \
        _Pragma("unroll")                                                            \
        for (int mt = 0; mt < 4; ++mt)                                               \
            _Pragma("unroll")                                                        \
            for (int nt = 0; nt < 2; ++nt) {                                         \
                float p0 = __builtin_amdgcn_exp2f(st[mt][nt][0]);                    \
                float p1 = __builtin_amdgcn_exp2f(st[mt][nt][1]);                    \
                float p2 = __builtin_amdgcn_exp2f(st[mt][nt][2]);                    \
                float p3 = __builtin_amdgcn_exp2f(st[mt][nt][3]);                    \
                lsum[nt] += (p0 + p1) + (p2 + p3);                                   \
                u32x2 pw = { pack_trunc(p0, p1), pack_trunc(p2, p3) };               \
                *(u32x2*)&Psc[wv][(nt * 16 + l15) * 64 + ((mt * 16 + 4 * qd) ^ key8)] = pw; \
            }                                                                        \
        _Pragma("unroll")                                                            \
        for (int mk = 0; mk < 2; ++mk) {                                             \
            bf16x8 ap[2];                                                            \
            _Pragma("unroll")                                                        \
            for (int nt = 0; nt < 2; ++nt)                                           \
                ap[nt] = *(const bf16x8*)&Psc[wv][(nt * 16 + l15) * 64 + ((mk * 32 + qd * 8) ^ key8)]; \
            _Pragma("unroll")                                                        \
            for (int ct = 0; ct < 4; ++ct) {                                         \
                bf16x8 bv = *(const bf16x8*)&Vt[nb][sj][(ct * 16 + l15) * 64 + ((mk * 32 + qd * 8) ^ key8)]; \
                _Pragma("unroll")                                                    \
                for (int nt = 0; nt < 2; ++nt)                                       \
                    Oacc[nt][ct] = __builtin_amdgcn_mfma_f32_16x16x32_bf16(ap[nt], bv, Oacc[nt][ct], 0, 0, 0); \
            }                                                                        \
        }                                                                            \
    }

    ASTAGE(0, 0)
    #pragma unroll 1
    for (int m0 = 0; m0 < NTOK; m0 += 256) {
        __syncthreads();                    // buf0 (keys m0..m0+127) ready; buf1 free
        ASTAGE(1, m0 + 128)
        ACOMP(0, 0) ACOMP(0, 1)
        __syncthreads();                    // buf1 ready; buf0 free
        if (m0 + 256 < NTOK) { ASTAGE(0, m0 + 256) }
        ACOMP(1, 0) ACOMP(1, 1)
    }
    #undef ASTAGE
    #undef ACOMP

    // ---- coalesced O epilogue: stage per-wave [tok 32][ch 64] in Psc, write 128B rows ----
    #pragma unroll
    for (int nt = 0; nt < 2; ++nt) {
        lsum[nt] += __shfl_xor(lsum[nt], 16);
        lsum[nt] += __shfl_xor(lsum[nt], 32);
        float inv = 1.f / lsum[nt];
        #pragma unroll
        for (int r = 0; r < 4; ++r) {
            float ir = __shfl(inv, 4 * qd + r);
            #pragma unroll
            for (int ct = 0; ct < 4; ++ct)
                Psc[wv][(nt * 16 + qd * 4 + r) * 64 + ct * 16 + l15] =
                    f2bf(Oacc[nt][ct][r] * ir);
        }
    }
    __syncthreads();   // order LDS stage before copy (also covers cross-lane visibility)
    int orw = L >> 1, ohf = L & 1;          // 32 rows x 2 halves of 32 ch
    const unsigned short* osrc = &Psc[wv][orw * 64 + ohf * 32];
    unsigned short* odst = qk + ((size_t)b * NTOK + q0 + wv * 32 + orw) * 1024 + h * 64 + ohf * 32;
    *(u16x8*)(odst)     = *(const u16x8*)(osrc);
    *(u16x8*)(odst + 8) = *(const u16x8*)(osrc + 8);
    *(u16x8*)(odst + 16) = *(const u16x8*)(osrc + 16);
    *(u16x8*)(odst + 24) = *(const u16x8*)(osrc + 24);
}

extern "C" void kernel_launch(void* const* d_in, const int* in_sizes, int n_in,
                              void* d_out, int out_size, void* d_ws, size_t ws_size,
                              hipStream_t stream) {
    const float* x      = (const float*)d_in[0];
    const float* norm_w = (const float*)d_in[1];
    const float* norm_b = (const float*)d_in[2];
    const float* qkv_w  = (const float*)d_in[3];
    const float* qkv_b  = (const float*)d_in[4];
    const float* proj_w = (const float*)d_in[5];
    const float* proj_b = (const float*)d_in[6];
    float* out = (float*)d_out;

    // ws: qk 16MB | vb 8MB | wp 512KB | bp 1KB | pad | xb16 16MB
    const size_t QK_B = (size_t)NB * NTOK * 1024 * 2;        // 16,777,216
    const size_t VB_B = (size_t)NB * 8 * 64 * NTOK * 2;      //  8,388,608
    const size_t XB_OFF = QK_B + VB_B + 1048576;
    if (ws_size < XB_OFF + (size_t)NB * CH * NTOK * 2) return;
    unsigned short* qk = (unsigned short*)d_ws;
    unsigned short* vb = (unsigned short*)((char*)d_ws + QK_B);
    unsigned short* wp = (unsigned short*)((char*)d_ws + QK_B + VB_B);
    unsigned short* bp = (unsigned short*)((char*)d_ws + QK_B + VB_B + 524288);
    unsigned short* xb16 = (unsigned short*)((char*)d_ws + XB_OFF);

    // d_out scratch (dead until proj writes): xn 8 MB | wq 1.5 MB | bq 3 KB
    unsigned short* xn = (unsigned short*)d_out;
    unsigned short* wq = (unsigned short*)((char*)d_out + 8388608);
    unsigned short* bq = (unsigned short*)((char*)d_out + 9961472);

    prep_kernel<<<dim3(4361), dim3(256), 0, stream>>>(
        x, xb16, norm_w, norm_b, qkv_w, qkv_b, proj_w, proj_b, wq, bq, wp, bp, xn);
    qkv_gemm<<<dim3(8, 12, NB), dim3(256), 0, stream>>>(xn, wq, bq, qk, vb);
    attn_kernel<<<dim3(64, 8, 1), dim3(256), 0, stream>>>(qk, vb);
    proj_gemm<<<dim3(16, 4, NB), dim3(256), 0, stream>>>(qk, wp, bp, xb16, out);
}